// Round 4
// baseline (1736.858 us; speedup 1.0000x reference)
//
#include <hip/hip_runtime.h>
#include <math.h>

#define DIM 64
#define PART_T 2048
#define BK_SHIFT 9
#define BK_SPAN 512    // 1 << BK_SHIFT; K = ceil(N/512) must be <= 256
#define BK_CAP 8192    // fixed per-bucket edge capacity (mean 6377, sigma ~80)
#define QN 128         // dst nodes per scatter block (quarter bucket)
#define AST 65         // LDS accumulator row stride in floats (65 -> bank = dst%32 spread)
#define TILE_SHIFT 14  // src tile = s >> 14: 16K nodes = 2 MB of fp16 rows (fits XCD L2)
#define SORT_T 1024

typedef _Float16 half8 __attribute__((ext_vector_type(8)));

// ---- cross-lane helpers ----

__device__ __forceinline__ float dpp_sum8_f32(float v) {
    int x = __float_as_int(v);
    v += __int_as_float(__builtin_amdgcn_update_dpp(0, x, 0xB1, 0xF, 0xF, true));
    x = __float_as_int(v);
    v += __int_as_float(__builtin_amdgcn_update_dpp(0, x, 0x4E, 0xF, 0xF, true));
    x = __float_as_int(v);
    v += __int_as_float(__builtin_amdgcn_update_dpp(0, x, 0x141, 0xF, 0xF, true));
    return v;
}

// wave-level inclusive scan (no barriers)
__device__ __forceinline__ int wave_incl_scan(int v) {
    int lane = threadIdx.x & 63;
    #pragma unroll
    for (int d = 1; d < 64; d <<= 1) {
        int n = __shfl_up(v, d, 64);
        if (lane >= d) v += n;
    }
    return v;
}

// block-wide exclusive scan over 256 threads; wsum = 4-int LDS scratch.
__device__ __forceinline__ int block_scan_excl(int v, int* wsum) {
    int incl = wave_incl_scan(v);
    int w = threadIdx.x >> 6;
    if ((threadIdx.x & 63) == 63) wsum[w] = incl;
    __syncthreads();
    int offset = 0;
    #pragma unroll
    for (int i = 0; i < 3; ++i) offset += (i < w) ? wsum[i] : 0;
    return offset + incl - v;
}

// ---------------- cursor init (fixed bucket bases) ----------------

__global__ void init_kernel(int* __restrict__ gcursor, int K) {
    int t = threadIdx.x;
    if (t < K) gcursor[t] = t * BK_CAP;
}

// ---------------- Phase A: partition edges into K coarse buckets ----------------
// Record: src (17b) | dst_local (9b) << 17  — fits 4B for N < 131072.

__global__ void part_kernel(const int* __restrict__ src, const int* __restrict__ dst,
                            int* __restrict__ gcursor, unsigned int* __restrict__ part,
                            int E, int K) {
    __shared__ unsigned int tmp_rec[PART_T];
    __shared__ unsigned char tmp_bkt[PART_T];
    __shared__ int hist[256];
    __shared__ int lstart[256];
    __shared__ int cursor[256];
    __shared__ int gbase[256];
    __shared__ int wsum[4];
    int t = threadIdx.x;
    int tile = blockIdx.x * PART_T;
    int n = E - tile; if (n > PART_T) n = PART_T;

    hist[t] = 0;
    __syncthreads();

    for (int i = t; i < n; i += 256) {
        int s = src[tile + i];
        int d = dst[tile + i];
        int b = d >> BK_SHIFT;
        tmp_rec[i] = (unsigned int)s | ((unsigned int)(d & (BK_SPAN - 1)) << 17);
        tmp_bkt[i] = (unsigned char)b;
        atomicAdd(&hist[b], 1);
    }
    __syncthreads();

    int hv = hist[t];
    int excl = block_scan_excl(hv, wsum);
    lstart[t] = excl;
    cursor[t] = excl;
    if (t < K && hv > 0) gbase[t] = atomicAdd(&gcursor[t], hv);
    __syncthreads();

    for (int i = t; i < n; i += 256) {
        int b = tmp_bkt[i];
        int r = atomicAdd(&cursor[b], 1);
        part[gbase[b] + (r - lstart[b])] = tmp_rec[i];
    }
}

// ---------------- Phase B: per-bucket (quarter, src-tile) sort + dis + fused conv ----------------
// Sort key = (dst_local>>7)*8 | (src>>TILE_SHIFT): groups records by dst quarter,
// then by 2MB src tile -> scatter blocks sweep tiles in phase (L2-resident window).
// Also: per-node degree -> dis; g0 = dis * emb (fp16).

__global__ __launch_bounds__(SORT_T)
void sort_kernel(const unsigned int* __restrict__ part, const int* __restrict__ gcursor,
                 unsigned int* __restrict__ part2, int2* __restrict__ qspan,
                 float* __restrict__ dis,
                 const float* __restrict__ emb, half8* __restrict__ g0, int N) {
    __shared__ int deg[BK_SPAN];
    __shared__ float sdis[BK_SPAN];
    __shared__ int bins[32];
    __shared__ int binpfx[33];
    __shared__ int cur[32];
    int b = blockIdx.x;
    int t = threadIdx.x;
    int pbase = b * BK_CAP;
    int cnt   = gcursor[b] - pbase;
    int nodeBase = b << BK_SHIFT;

    if (t < BK_SPAN) deg[t] = 0;
    if (t < 32) bins[t] = 0;
    __syncthreads();

    // pass 1: degree + key histogram (LDS atomics)
    for (int j = t; j < cnt; j += SORT_T) {
        unsigned int rec = part[pbase + j];
        int dl = (int)(rec >> 17);
        int s  = (int)(rec & 0x1FFFFu);
        atomicAdd(&deg[dl], 1);
        atomicAdd(&bins[(dl >> 7) * 8 + (s >> TILE_SHIFT)], 1);
    }
    __syncthreads();

    // dis
    if (t < BK_SPAN) {
        int d0 = deg[t];
        float f0 = d0 > 0 ? rsqrtf((float)d0) : 0.0f;
        sdis[t] = f0;
        int i0 = nodeBase + t;
        if (i0 < N) dis[i0] = f0;
    }
    // 32-bin exclusive scan (serial, trivial)
    if (t == 0) {
        int run = 0;
        #pragma unroll
        for (int k = 0; k < 32; ++k) { binpfx[k] = run; run += bins[k]; }
        binpfx[32] = run;
    }
    __syncthreads();
    if (t < 32) cur[t] = binpfx[t];
    if (t < 4)  qspan[b * 4 + t] = make_int2(pbase + binpfx[t * 8], pbase + binpfx[(t + 1) * 8]);
    __syncthreads();

    // pass 2: place sorted records (bucket-private span -> write-combined)
    for (int j = t; j < cnt; j += SORT_T) {
        unsigned int rec = part[pbase + j];
        int dl = (int)(rec >> 17);
        int s  = (int)(rec & 0x1FFFFu);
        int key = (dl >> 7) * 8 + (s >> TILE_SHIFT);
        int p = atomicAdd(&cur[key], 1);
        part2[pbase + p] = rec;
    }

    // fused conv: g0 = dis * emb for this bucket (emb read coalesced, dis from LDS)
    const float4* e4 = (const float4*)emb;
    int nloc = N - nodeBase;
    if (nloc > BK_SPAN) nloc = BK_SPAN;
    if (nloc < 0) nloc = 0;
    int lim = nloc * 8;                  // half8 rows for this bucket
    for (int j = t; j < lim; j += SORT_T) {
        int r = j >> 3;                  // local node
        int v = nodeBase + r;
        float dv = sdis[r];
        float4 a = e4[(size_t)v * 16 + (size_t)(j & 7) * 2];
        float4 c = e4[(size_t)v * 16 + (size_t)(j & 7) * 2 + 1];
        half8 hh;
        hh[0] = (_Float16)(dv * a.x); hh[1] = (_Float16)(dv * a.y);
        hh[2] = (_Float16)(dv * a.z); hh[3] = (_Float16)(dv * a.w);
        hh[4] = (_Float16)(dv * c.x); hh[5] = (_Float16)(dv * c.y);
        hh[6] = (_Float16)(dv * c.z); hh[7] = (_Float16)(dv * c.w);
        g0[(size_t)v * 8 + (j & 7)] = hh;
    }
}

// ---------------- layer compute: scatter-SpMM into LDS fp32 accumulator ----------------
// Block = 128-dst-node quarter. Sweeps its tile-sorted edge span front-to-back:
// all blocks stay roughly in phase -> hot 2MB src-tile window is L2-resident.
// 8 lanes/edge, dim-rotation (l+dst)&7 decorrelates LDS banks; stride-65 rows
// add dst%32 bank spread. gout[v] = dis[v]^2 * acc[v].

__device__ __forceinline__ void scatter_accum(const unsigned int* __restrict__ part2,
                                              int2 sp, const half8* __restrict__ gin,
                                              float* acc) {
    int t = threadIdx.x;
    int l = t & 7;
    int g = t >> 3;                      // 32 edge groups
    for (int j = sp.x + g; j < sp.y; j += 32) {
        unsigned int rec = part2[j];
        int dl = (int)((rec >> 17) & (QN - 1));
        int s  = (int)(rec & 0x1FFFFu);
        int rot = (l + dl) & 7;
        half8 row = gin[(size_t)s * 8 + rot];
        int base = dl * AST + rot * 8;
        #pragma unroll
        for (int m = 0; m < 8; ++m) atomicAdd(&acc[base + m], (float)row[m]);
    }
}

__global__ __launch_bounds__(256)
void spmm_scatter_kernel(const unsigned int* __restrict__ part2, const int2* __restrict__ qspan,
                         const float* __restrict__ dis,
                         const half8* __restrict__ gin, half8* __restrict__ gout, int N) {
    __shared__ float acc[QN * AST];      // 33.3 KB -> 4 blocks/CU
    int t = threadIdx.x;
    for (int i = t; i < QN * AST; i += 256) acc[i] = 0.0f;
    __syncthreads();

    int2 sp = qspan[blockIdx.x];
    scatter_accum(part2, sp, gin, acc);
    __syncthreads();

    int nodeBase = (blockIdx.x >> 2) * BK_SPAN + (blockIdx.x & 3) * QN;
    for (int pos = t; pos < QN * 8; pos += 256) {
        int r  = pos >> 3;
        int ll = pos & 7;
        int v = nodeBase + r;
        if (v < N) {
            float d = dis[v];
            float d2 = d * d;
            const float* ap = &acc[r * AST + ll * 8];
            half8 o;
            #pragma unroll
            for (int m = 0; m < 8; ++m) o[m] = (_Float16)(d2 * ap[m]);
            gout[(size_t)v * 8 + ll] = o;
        }
    }
}

__device__ __forceinline__ void softmax4(const float* __restrict__ alpha, float* w) {
    float a0 = alpha[0], a1 = alpha[1], a2 = alpha[2], a3 = alpha[3];
    float m = fmaxf(fmaxf(a0, a1), fmaxf(a2, a3));
    float e0 = expf(a0 - m), e1 = expf(a1 - m), e2 = expf(a2 - m), e3 = expf(a3 - m);
    float s = 1.0f / (e0 + e1 + e2 + e3);
    w[0] = e0 * s; w[1] = e1 * s; w[2] = e2 * s; w[3] = e3 * s;
}

// last layer: scatter-accumulate g2 -> acc, then fused combine epilogue (all coalesced)
__global__ __launch_bounds__(256)
void spmm_final_scatter_kernel(const unsigned int* __restrict__ part2, const int2* __restrict__ qspan,
                               const float* __restrict__ dis, const float* __restrict__ emb,
                               const half8* __restrict__ g1, const half8* __restrict__ g2,
                               half8* __restrict__ out, const float* __restrict__ alpha, int N) {
    __shared__ float acc[QN * AST];
    int t = threadIdx.x;
    for (int i = t; i < QN * AST; i += 256) acc[i] = 0.0f;
    __syncthreads();

    int2 sp = qspan[blockIdx.x];
    scatter_accum(part2, sp, g2, acc);
    __syncthreads();

    float w[4];
    softmax4(alpha, w);
    int nodeBase = (blockIdx.x >> 2) * BK_SPAN + (blockIdx.x & 3) * QN;
    const float4* e4 = (const float4*)emb;
    for (int pos = t; pos < QN * 8; pos += 256) {
        int r  = pos >> 3;
        int ll = pos & 7;
        int v = nodeBase + r;
        if (v < N) {
            float d  = dis[v];
            float iv = d > 0.0f ? 1.0f / d : 0.0f;   // invdis = sqrt(deg)
            float4 ea = e4[(size_t)v * 16 + ll * 2];
            float4 eb = e4[(size_t)v * 16 + ll * 2 + 1];
            half8 h1 = g1[(size_t)v * 8 + ll];
            half8 h2 = g2[(size_t)v * 8 + ll];
            const float* ap = &acc[r * AST + ll * 8];
            float ef[8] = {ea.x, ea.y, ea.z, ea.w, eb.x, eb.y, eb.z, eb.w};
            half8 o;
            #pragma unroll
            for (int m = 0; m < 8; ++m) {
                float x1 = (float)h1[m] * iv;
                float x2 = (float)h2[m] * iv;
                float x3 = d * ap[m];
                float val = w[0] * ef[m] + w[1] * x1 + w[2] * x2 + w[3] * x3;
                o[m] = (_Float16)val;
            }
            out[(size_t)v * 8 + ll] = o;
        }
    }
}

// res[e] = dot(out[a[e]], out[b[e]]) ; fdot2 + DPP 8-lane reduction
__global__ void dot_kernel(const int* __restrict__ a, const int* __restrict__ b,
                           const half8* __restrict__ out, float* __restrict__ res, int E) {
    long long g = (long long)blockIdx.x * blockDim.x + threadIdx.x;
    int e   = (int)(g >> 3);
    int sub = (int)(g & 7);
    if (e >= E) return;
    int ia = a[e];
    int ib = b[e];
    half8 va = out[(size_t)ia * 8 + sub];
    half8 vb = out[(size_t)ib * 8 + sub];
#if __has_builtin(__builtin_amdgcn_fdot2)
    float v = 0.f;
    v = __builtin_amdgcn_fdot2(__builtin_shufflevector(va, va, 0, 1),
                               __builtin_shufflevector(vb, vb, 0, 1), v, false);
    v = __builtin_amdgcn_fdot2(__builtin_shufflevector(va, va, 2, 3),
                               __builtin_shufflevector(vb, vb, 2, 3), v, false);
    v = __builtin_amdgcn_fdot2(__builtin_shufflevector(va, va, 4, 5),
                               __builtin_shufflevector(vb, vb, 4, 5), v, false);
    v = __builtin_amdgcn_fdot2(__builtin_shufflevector(va, va, 6, 7),
                               __builtin_shufflevector(vb, vb, 6, 7), v, false);
#else
    float v = 0.f;
    #pragma unroll
    for (int k = 0; k < 8; ++k) v += (float)va[k] * (float)vb[k];
#endif
    v = dpp_sum8_f32(v);
    if (sub == 0) res[e] = v;
}

// ---------------- launcher ----------------

static inline size_t align256(size_t x) { return (x + 255) & ~(size_t)255; }

extern "C" void kernel_launch(void* const* d_in, const int* in_sizes, int n_in,
                              void* d_out, int out_size, void* d_ws, size_t ws_size,
                              hipStream_t stream) {
    const int* edge_index = (const int*)d_in[0];       // [2, E]
    const int* edge_label = (const int*)d_in[1];       // [2, E]
    const float* emb      = (const float*)d_in[2];     // [N, D]
    const float* alpha    = (const float*)d_in[3];     // [L+1]

    const int E = in_sizes[0] / 2;
    const int N = in_sizes[2] / DIM;
    const int K = (N + BK_SPAN - 1) >> BK_SHIFT;       // coarse buckets (<=256)

    const int* src = edge_index;
    const int* dst = edge_index + E;
    const int* la  = edge_label;
    const int* lb  = edge_label + E;

    // workspace layout (~52 MB; outbuf aliases g0 which is dead after layer 1)
    char* ws = (char*)d_ws;
    size_t off = 0;
    float* dis     = (float*)(ws + off); off = align256(off + (size_t)N * 4);
    int*   gcursor = (int*)(ws + off);   off = align256(off + (size_t)256 * 4);
    int2*  qspan   = (int2*)(ws + off);  off = align256(off + (size_t)K * 4 * 8);
    unsigned int* part  = (unsigned int*)(ws + off); off = align256(off + (size_t)K * BK_CAP * 4);
    unsigned int* part2 = (unsigned int*)(ws + off); off = align256(off + (size_t)K * BK_CAP * 4);
    half8* g0      = (half8*)(ws + off); off = align256(off + (size_t)(N + 1) * DIM * 2);
    half8* g1      = (half8*)(ws + off); off = align256(off + (size_t)(N + 1) * DIM * 2);
    half8* g2      = (half8*)(ws + off); off = align256(off + (size_t)(N + 1) * DIM * 2);
    half8* outbuf  = g0;                 // alias: g0 dead after spmm layer 1
    (void)ws_size;

    const int B = 256;
    const int gridT = (E + PART_T - 1) / PART_T;

    // 1. fixed bucket bases
    init_kernel<<<1, B, 0, stream>>>(gcursor, K);

    // 2. Phase A partition (2-pass, direct bucket-span writes)
    part_kernel<<<gridT, B, 0, stream>>>(src, dst, gcursor, part, E, K);

    // 3. Phase B: (quarter, src-tile) sort + dis + fused conv (g0)
    sort_kernel<<<K, SORT_T, 0, stream>>>(part, gcursor, part2, qspan, dis, emb, g0, N);

    // 4. three scatter-SpMM layers (block = 128-node quarter, LDS fp32 accumulate)
    const int gridS = K * 4;
    spmm_scatter_kernel<<<gridS, B, 0, stream>>>(part2, qspan, dis, g0, g1, N);
    spmm_scatter_kernel<<<gridS, B, 0, stream>>>(part2, qspan, dis, g1, g2, N);
    spmm_final_scatter_kernel<<<gridS, B, 0, stream>>>(part2, qspan, dis, emb, g1, g2,
                                                       outbuf, alpha, N);

    // 5. per-edge dot products
    const long long dthreads = (long long)E * 8;
    const int gridD = (int)((dthreads + B - 1) / B);
    dot_kernel<<<gridD, B, 0, stream>>>(la, lb, outbuf, (float*)d_out, E);
}

// Round 5
// 416.683 us; speedup vs baseline: 4.1683x; 4.1683x over previous
//
#include <hip/hip_runtime.h>
#include <math.h>

#define DIM 64
#define PART_T 2048
#define BK_SHIFT 9
#define BK_SPAN 512    // 1 << BK_SHIFT; K = ceil(N/512) must be <= 256
#define BK_CAP 8192    // fixed per-bucket edge capacity (mean 6377, sigma ~80 -> 22 sigma)
#define BK_PAD 2048    // per-bucket padding allowance (>= 4*512)
#define BK_REG (BK_CAP + BK_PAD)
#define CSR_T 1024     // csr_kernel block size

typedef _Float16 half8 __attribute__((ext_vector_type(8)));

// Sliced feature layout: 4 quarter-slices of 16 dims. Slice q holds, for every
// node v, 2 half8 units: g[((size_t)q*(N+1) + v)*2 + h], h in {0,1}.
// One slice = (N+1)*32 B ~= 3.2 MB -> fits a 4 MiB per-XCD L2.

// ---- cross-lane helpers ----

__device__ __forceinline__ half8 shfl_xor_h8(half8 v, int mask) {
    int4 iv;
    __builtin_memcpy(&iv, &v, 16);
    iv.x = __shfl_xor(iv.x, mask, 64);
    iv.y = __shfl_xor(iv.y, mask, 64);
    iv.z = __shfl_xor(iv.z, mask, 64);
    iv.w = __shfl_xor(iv.w, mask, 64);
    half8 r;
    __builtin_memcpy(&r, &iv, 16);
    return r;
}

// wave-level inclusive scan (no barriers)
__device__ __forceinline__ int wave_incl_scan(int v) {
    int lane = threadIdx.x & 63;
    #pragma unroll
    for (int d = 1; d < 64; d <<= 1) {
        int n = __shfl_up(v, d, 64);
        if (lane >= d) v += n;
    }
    return v;
}

// block-wide exclusive scan over 256 threads; wsum = 4-int LDS scratch.
__device__ __forceinline__ int block_scan_excl(int v, int* wsum) {
    int incl = wave_incl_scan(v);
    int w = threadIdx.x >> 6;
    if ((threadIdx.x & 63) == 63) wsum[w] = incl;
    __syncthreads();
    int offset = 0;
    #pragma unroll
    for (int i = 0; i < 3; ++i) offset += (i < w) ? wsum[i] : 0;
    return offset + incl - v;
}

// block-wide exclusive scan over NW waves (NW*64 threads); wsum = NW-int LDS scratch.
template <int NW>
__device__ __forceinline__ int block_scan_excl_n(int v, int* wsum) {
    int incl = wave_incl_scan(v);
    int w = threadIdx.x >> 6;
    if ((threadIdx.x & 63) == 63) wsum[w] = incl;
    __syncthreads();
    int offset = 0;
    #pragma unroll
    for (int i = 0; i < NW - 1; ++i) offset += (i < w) ? wsum[i] : 0;
    return offset + incl - v;
}

// ---------------- cursor init (fixed bucket bases) + dummy-row zero ----------------

__global__ void init_kernel(int* __restrict__ gcursor, int K,
                            half8* __restrict__ g0, half8* __restrict__ g1,
                            half8* __restrict__ g2, int N) {
    int t = threadIdx.x;
    if (t < K) gcursor[t] = t * BK_CAP;
    if (t < 8) {                         // q = t>>1, h = t&1 : dummy row v=N per slice
        half8 z = (half8)(_Float16)0;
        size_t idx = ((size_t)(t >> 1) * (N + 1) + N) * 2 + (t & 1);
        g0[idx] = z;
        g1[idx] = z;
        g2[idx] = z;
    }
}

// ---------------- Phase A: partition edges into K coarse buckets ----------------
// Record: src (17b) | dst_local (9b) << 17  — fits 4B for N < 131072.

__global__ void part_kernel(const int* __restrict__ src, const int* __restrict__ dst,
                            int* __restrict__ gcursor, unsigned int* __restrict__ part,
                            int E, int K) {
    __shared__ unsigned int tmp_rec[PART_T];
    __shared__ unsigned char tmp_bkt[PART_T];
    __shared__ int hist[256];
    __shared__ int lstart[256];
    __shared__ int cursor[256];
    __shared__ int gbase[256];
    __shared__ int wsum[4];
    int t = threadIdx.x;
    int tile = blockIdx.x * PART_T;
    int n = E - tile; if (n > PART_T) n = PART_T;

    hist[t] = 0;
    __syncthreads();

    for (int i = t; i < n; i += 256) {
        int s = src[tile + i];
        int d = dst[tile + i];
        int b = d >> BK_SHIFT;
        tmp_rec[i] = (unsigned int)s | ((unsigned int)(d & (BK_SPAN - 1)) << 17);
        tmp_bkt[i] = (unsigned char)b;
        atomicAdd(&hist[b], 1);
    }
    __syncthreads();

    int hv = hist[t];
    int excl = block_scan_excl(hv, wsum);
    lstart[t] = excl;
    cursor[t] = excl;
    if (t < K && hv > 0) gbase[t] = atomicAdd(&gcursor[t], hv);
    __syncthreads();

    for (int i = t; i < n; i += 256) {
        int b = tmp_bkt[i];
        int r = atomicAdd(&cursor[b], 1);
        part[gbase[b] + (r - lstart[b])] = tmp_rec[i];
    }
}

// ---------------- Phase B: per-bucket degree + padded CSR + dis + fused conv ----------------
// Each node's edge run padded to a multiple of 4 with dummy src = N (zero row).
// Fused: g0 = dis * emb (fp16), written in SLICED layout.

__global__ __launch_bounds__(CSR_T)
void csr_kernel(const unsigned int* __restrict__ part, const int* __restrict__ gcursor,
                int2* __restrict__ prange, int* __restrict__ csr_src,
                float* __restrict__ dis,
                const float* __restrict__ emb, half8* __restrict__ g0, int N) {
    __shared__ int h[BK_SPAN];        // degree -> placement cursor (relative)
    __shared__ int pfx[BK_SPAN + 1];  // padded exclusive prefix (relative)
    __shared__ float sdis[BK_SPAN];
    __shared__ int wsum[CSR_T / 64];
    int b = blockIdx.x;
    int t = threadIdx.x;
    int pbase = b * BK_CAP;
    int cnt   = gcursor[b] - pbase;
    int qbase = b * BK_REG;
    int nodeBase = b << BK_SHIFT;

    if (t < BK_SPAN) h[t] = 0;
    __syncthreads();

    // per-node degree histogram (LDS atomics only)
    for (int j = t; j < cnt; j += CSR_T) {
        unsigned int rec = part[pbase + j];
        atomicAdd(&h[rec >> 17], 1);
    }
    __syncthreads();

    // dis from degree; padded-degree scan
    int d0 = (t < BK_SPAN) ? h[t] : 0;
    if (t < BK_SPAN) {
        float f0 = d0 > 0 ? rsqrtf((float)d0) : 0.0f;
        int i0 = nodeBase + t;
        if (i0 < N) dis[i0] = f0;
        sdis[t] = f0;
    }
    int p0 = (d0 + 3) & ~3;
    int excl = block_scan_excl_n<CSR_T / 64>(p0, wsum);  // internal __syncthreads
    if (t < BK_SPAN) {
        pfx[t] = excl;
        h[t]   = excl;                // placement cursor (relative start)
    }
    if (t == BK_SPAN - 1) pfx[BK_SPAN] = excl + p0;
    __syncthreads();

    // prange (coalesced int2 store)
    if (t < BK_SPAN) {
        int idx = nodeBase + t;
        if (idx < N) prange[idx] = make_int2(qbase + pfx[t], qbase + pfx[t + 1]);
    }
    __syncthreads();

    // place records (bucket-private span -> single-CU write combining)
    for (int j = t; j < cnt; j += CSR_T) {
        unsigned int rec = part[pbase + j];
        int dl = (int)(rec >> 17);
        int s  = (int)(rec & 0x1FFFFu);
        int p = atomicAdd(&h[dl], 1);
        csr_src[qbase + p] = s;
    }
    __syncthreads();

    // pad fill: dummy src = N (<= 3 per node)
    if (t < BK_SPAN) {
        int endp = pfx[t + 1];
        for (int p = h[t]; p < endp; ++p) csr_src[qbase + p] = N;
    }

    // fused conv: g0 = dis * emb for this bucket, SLICED layout
    const float4* e4 = (const float4*)emb;
    int nloc = N - nodeBase;
    if (nloc > BK_SPAN) nloc = BK_SPAN;
    if (nloc < 0) nloc = 0;
    int lim = nloc * 8;                  // half8 units for this bucket
    for (int j = t; j < lim; j += CSR_T) {
        int r   = j >> 3;                // local node
        int sub = j & 7;                 // original half8 index 0..7
        int v = nodeBase + r;
        float dv = sdis[r];
        float4 a = e4[(size_t)v * 16 + (size_t)sub * 2];
        float4 c = e4[(size_t)v * 16 + (size_t)sub * 2 + 1];
        half8 hh;
        hh[0] = (_Float16)(dv * a.x); hh[1] = (_Float16)(dv * a.y);
        hh[2] = (_Float16)(dv * a.z); hh[3] = (_Float16)(dv * a.w);
        hh[4] = (_Float16)(dv * c.x); hh[5] = (_Float16)(dv * c.y);
        hh[6] = (_Float16)(dv * c.z); hh[7] = (_Float16)(dv * c.w);
        int q  = sub >> 1;
        int hp = sub & 1;
        g0[((size_t)q * (N + 1) + v) * 2 + hp] = hh;
    }
}

// ---------------- layer compute: quarter-sliced gather SpMM ----------------
// One pass handles 16 dims (one 3.2 MB slice -> L2-resident in every XCD).
// 2 nodes/wave, 16 edge slots x 2 sub-lanes (16 B each).

__global__ __launch_bounds__(256)
void spmm_q_kernel(const int2* __restrict__ prange, const int* __restrict__ csr_src,
                   const float* __restrict__ dis,
                   const half8* __restrict__ gin, half8* __restrict__ gout,
                   int N, int q) {
    int lane = threadIdx.x & 63;
    int wave = blockIdx.x * (blockDim.x >> 6) + (threadIdx.x >> 6);
    int v = wave * 2 + (lane >> 5);
    int slot = (lane >> 1) & 15;
    int sub  = lane & 1;
    bool valid = v < N;
    int beg = 0, end = 0;
    if (valid) { int2 pr = prange[v]; beg = pr.x; end = pr.y; }
    const half8* gq = gin + (size_t)q * (N + 1) * 2;
    half8 acc = (half8)(_Float16)0;
    for (int j = beg + slot; j < end; j += 16) {
        int s = csr_src[j];
        acc = acc + gq[(size_t)s * 2 + sub];
    }
    // reduce over 16 slots (masks 2,4,8,16 stay within the 32-lane node group)
    acc = acc + shfl_xor_h8(acc, 2);
    acc = acc + shfl_xor_h8(acc, 4);
    acc = acc + shfl_xor_h8(acc, 8);
    acc = acc + shfl_xor_h8(acc, 16);
    if (valid && (lane & 31) < 2) {
        float d = dis[v];
        float d2 = d * d;
        half8 o;
        #pragma unroll
        for (int k = 0; k < 8; ++k) o[k] = (_Float16)(d2 * (float)acc[k]);
        gout[((size_t)q * (N + 1) + v) * 2 + sub] = o;
    }
}

__device__ __forceinline__ void softmax4(const float* __restrict__ alpha, float* w) {
    float a0 = alpha[0], a1 = alpha[1], a2 = alpha[2], a3 = alpha[3];
    float m = fmaxf(fmaxf(a0, a1), fmaxf(a2, a3));
    float e0 = expf(a0 - m), e1 = expf(a1 - m), e2 = expf(a2 - m), e3 = expf(a3 - m);
    float s = 1.0f / (e0 + e1 + e2 + e3);
    w[0] = e0 * s; w[1] = e1 * s; w[2] = e2 * s; w[3] = e3 * s;
}

// last layer + fused combine for one quarter; out stored fp16, sliced
__global__ __launch_bounds__(256)
void spmm_final_q_kernel(const int2* __restrict__ prange, const int* __restrict__ csr_src,
                         const float* __restrict__ dis,
                         const float* __restrict__ emb, const half8* __restrict__ g1,
                         const half8* __restrict__ g2, half8* __restrict__ out,
                         const float* __restrict__ alpha, int N, int q) {
    int lane = threadIdx.x & 63;
    int wave = blockIdx.x * (blockDim.x >> 6) + (threadIdx.x >> 6);
    int v = wave * 2 + (lane >> 5);
    int slot = (lane >> 1) & 15;
    int sub  = lane & 1;
    bool valid = v < N;
    int beg = 0, end = 0;
    if (valid) { int2 pr = prange[v]; beg = pr.x; end = pr.y; }
    const half8* g2q = g2 + (size_t)q * (N + 1) * 2;
    half8 acc = (half8)(_Float16)0;
    for (int j = beg + slot; j < end; j += 16) {
        int s = csr_src[j];
        acc = acc + g2q[(size_t)s * 2 + sub];
    }
    acc = acc + shfl_xor_h8(acc, 2);
    acc = acc + shfl_xor_h8(acc, 4);
    acc = acc + shfl_xor_h8(acc, 8);
    acc = acc + shfl_xor_h8(acc, 16);
    if (valid && (lane & 31) < 2) {
        float w[4];
        softmax4(alpha, w);
        float d  = dis[v];
        float iv = d > 0.0f ? 1.0f / d : 0.0f;   // invdis = sqrt(deg)
        const float4* e4 = (const float4*)emb;
        float4 ea = e4[(size_t)v * 16 + q * 4 + sub * 2];
        float4 eb = e4[(size_t)v * 16 + q * 4 + sub * 2 + 1];
        size_t ridx = ((size_t)q * (N + 1) + v) * 2 + sub;
        half8 h1 = g1[ridx];
        half8 h2 = g2[ridx];
        float ef[8] = {ea.x, ea.y, ea.z, ea.w, eb.x, eb.y, eb.z, eb.w};
        half8 o;
        #pragma unroll
        for (int k = 0; k < 8; ++k) {
            float x1 = (float)h1[k] * iv;
            float x2 = (float)h2[k] * iv;
            float x3 = d * (float)acc[k];
            float val = w[0] * ef[k] + w[1] * x1 + w[2] * x2 + w[3] * x3;
            o[k] = (_Float16)val;
        }
        out[ridx] = o;
    }
}

// res[e] (+)= quarter-dot(out_q[a[e]], out_q[b[e]]) ; 2 lanes/edge, fdot2
__global__ void dot_q_kernel(const int* __restrict__ a, const int* __restrict__ b,
                             const half8* __restrict__ out, float* __restrict__ res,
                             int E, int N, int q) {
    long long g = (long long)blockIdx.x * blockDim.x + threadIdx.x;
    int e   = (int)(g >> 1);
    int sub = (int)(g & 1);
    if (e >= E) return;
    int ia = a[e];
    int ib = b[e];
    const half8* oq = out + (size_t)q * (N + 1) * 2;
    half8 va = oq[(size_t)ia * 2 + sub];
    half8 vb = oq[(size_t)ib * 2 + sub];
#if __has_builtin(__builtin_amdgcn_fdot2)
    float v = 0.f;
    v = __builtin_amdgcn_fdot2(__builtin_shufflevector(va, va, 0, 1),
                               __builtin_shufflevector(vb, vb, 0, 1), v, false);
    v = __builtin_amdgcn_fdot2(__builtin_shufflevector(va, va, 2, 3),
                               __builtin_shufflevector(vb, vb, 2, 3), v, false);
    v = __builtin_amdgcn_fdot2(__builtin_shufflevector(va, va, 4, 5),
                               __builtin_shufflevector(vb, vb, 4, 5), v, false);
    v = __builtin_amdgcn_fdot2(__builtin_shufflevector(va, va, 6, 7),
                               __builtin_shufflevector(vb, vb, 6, 7), v, false);
#else
    float v = 0.f;
    #pragma unroll
    for (int k = 0; k < 8; ++k) v += (float)va[k] * (float)vb[k];
#endif
    v += __shfl_xor(v, 1, 64);
    if (sub == 0) {
        if (q == 0) res[e] = v;
        else        res[e] += v;         // stream-ordered across passes: race-free
    }
}

// ---------------- launcher ----------------

static inline size_t align256(size_t x) { return (x + 255) & ~(size_t)255; }

extern "C" void kernel_launch(void* const* d_in, const int* in_sizes, int n_in,
                              void* d_out, int out_size, void* d_ws, size_t ws_size,
                              hipStream_t stream) {
    const int* edge_index = (const int*)d_in[0];       // [2, E]
    const int* edge_label = (const int*)d_in[1];       // [2, E]
    const float* emb      = (const float*)d_in[2];     // [N, D]
    const float* alpha    = (const float*)d_in[3];     // [L+1]

    const int E = in_sizes[0] / 2;
    const int N = in_sizes[2] / DIM;
    const int K = (N + BK_SPAN - 1) >> BK_SHIFT;       // coarse buckets (<=256)

    const int* src = edge_index;
    const int* dst = edge_index + E;
    const int* la  = edge_label;
    const int* lb  = edge_label + E;

    // workspace layout (~54 MB; outbuf aliases g0 which is dead after layer 1)
    char* ws = (char*)d_ws;
    size_t off = 0;
    float* dis     = (float*)(ws + off); off = align256(off + (size_t)N * 4);
    int2*  prange  = (int2*)(ws + off);  off = align256(off + (size_t)N * 8);
    int*   gcursor = (int*)(ws + off);   off = align256(off + (size_t)256 * 4);
    unsigned int* part = (unsigned int*)(ws + off); off = align256(off + (size_t)K * BK_CAP * 4);
    int*   csr_src = (int*)(ws + off);   off = align256(off + (size_t)K * BK_REG * 4);
    half8* g0      = (half8*)(ws + off); off = align256(off + (size_t)(N + 1) * DIM * 2);
    half8* g1      = (half8*)(ws + off); off = align256(off + (size_t)(N + 1) * DIM * 2);
    half8* g2      = (half8*)(ws + off); off = align256(off + (size_t)(N + 1) * DIM * 2);
    half8* outbuf  = g0;                 // alias: g0 dead after spmm layer 1
    (void)ws_size;

    const int B = 256;
    const int gridT = (E + PART_T - 1) / PART_T;

    // 1. fixed bucket bases + dummy-row zeroing (all 4 slices)
    init_kernel<<<1, B, 0, stream>>>(gcursor, K, g0, g1, g2, N);

    // 2. Phase A partition (2-pass, direct bucket-span writes)
    part_kernel<<<gridT, B, 0, stream>>>(src, dst, gcursor, part, E, K);

    // 3. Phase B: degree + dis + padded CSR + fused conv (sliced g0)
    csr_kernel<<<K, CSR_T, 0, stream>>>(part, gcursor, prange, csr_src, dis, emb, g0, N);

    // 4. gather-SpMM layers, 4 quarter passes each (slice L2-resident per pass)
    const int nodesPerBlock = (B / 64) * 2;
    const int gridS = (N + nodesPerBlock - 1) / nodesPerBlock;
    for (int q = 0; q < 4; ++q)
        spmm_q_kernel<<<gridS, B, 0, stream>>>(prange, csr_src, dis, g0, g1, N, q);
    for (int q = 0; q < 4; ++q)
        spmm_q_kernel<<<gridS, B, 0, stream>>>(prange, csr_src, dis, g1, g2, N, q);
    for (int q = 0; q < 4; ++q)
        spmm_final_q_kernel<<<gridS, B, 0, stream>>>(prange, csr_src, dis, emb, g1, g2,
                                                     outbuf, alpha, N, q);

    // 5. per-edge dot products, 4 quarter passes accumulating into res
    const long long dthreads = (long long)E * 2;
    const int gridD = (int)((dthreads + B - 1) / B);
    for (int q = 0; q < 4; ++q)
        dot_q_kernel<<<gridD, B, 0, stream>>>(la, lb, outbuf, (float*)d_out, E, N, q);
}

// Round 6
// 232.854 us; speedup vs baseline: 7.4590x; 1.7895x over previous
//
#include <hip/hip_runtime.h>
#include <math.h>

#define DIM 64
#define PART_T 2048
#define BK_SHIFT 9
#define BK_SPAN 512    // 1 << BK_SHIFT; K = ceil(N/512) must be <= 256
#define BK_CAP 8192    // fixed per-bucket edge capacity (mean 6377, sigma ~80 -> 22 sigma)
#define BK_PAD 2048    // per-bucket padding allowance (>= 4*512)
#define BK_REG (BK_CAP + BK_PAD)
#define CSR_T 1024     // csr_kernel block size
#define GRID_G 2048    // persistent grid for gather kernels

typedef _Float16 half8 __attribute__((ext_vector_type(8)));

// ---- cross-lane helpers ----

__device__ __forceinline__ half8 shfl_xor_h8(half8 v, int mask) {
    int4 iv;
    __builtin_memcpy(&iv, &v, 16);
    iv.x = __shfl_xor(iv.x, mask, 64);
    iv.y = __shfl_xor(iv.y, mask, 64);
    iv.z = __shfl_xor(iv.z, mask, 64);
    iv.w = __shfl_xor(iv.w, mask, 64);
    half8 r;
    __builtin_memcpy(&r, &iv, 16);
    return r;
}

__device__ __forceinline__ half8 dpp_ror8_h8(half8 v) {
    int4 iv;
    __builtin_memcpy(&iv, &v, 16);
    int4 r;
    r.x = __builtin_amdgcn_update_dpp(0, iv.x, 0x128, 0xF, 0xF, true);
    r.y = __builtin_amdgcn_update_dpp(0, iv.y, 0x128, 0xF, 0xF, true);
    r.z = __builtin_amdgcn_update_dpp(0, iv.z, 0x128, 0xF, 0xF, true);
    r.w = __builtin_amdgcn_update_dpp(0, iv.w, 0x128, 0xF, 0xF, true);
    half8 out;
    __builtin_memcpy(&out, &r, 16);
    return out;
}

__device__ __forceinline__ float dpp_sum8_f32(float v) {
    int x = __float_as_int(v);
    v += __int_as_float(__builtin_amdgcn_update_dpp(0, x, 0xB1, 0xF, 0xF, true));
    x = __float_as_int(v);
    v += __int_as_float(__builtin_amdgcn_update_dpp(0, x, 0x4E, 0xF, 0xF, true));
    x = __float_as_int(v);
    v += __int_as_float(__builtin_amdgcn_update_dpp(0, x, 0x141, 0xF, 0xF, true));
    return v;
}

// wave-level inclusive scan (no barriers)
__device__ __forceinline__ int wave_incl_scan(int v) {
    int lane = threadIdx.x & 63;
    #pragma unroll
    for (int d = 1; d < 64; d <<= 1) {
        int n = __shfl_up(v, d, 64);
        if (lane >= d) v += n;
    }
    return v;
}

// block-wide exclusive scan over 256 threads; wsum = 4-int LDS scratch.
__device__ __forceinline__ int block_scan_excl(int v, int* wsum) {
    int incl = wave_incl_scan(v);
    int w = threadIdx.x >> 6;
    if ((threadIdx.x & 63) == 63) wsum[w] = incl;
    __syncthreads();
    int offset = 0;
    #pragma unroll
    for (int i = 0; i < 3; ++i) offset += (i < w) ? wsum[i] : 0;
    return offset + incl - v;
}

// block-wide exclusive scan over NW waves (NW*64 threads); wsum = NW-int LDS scratch.
template <int NW>
__device__ __forceinline__ int block_scan_excl_n(int v, int* wsum) {
    int incl = wave_incl_scan(v);
    int w = threadIdx.x >> 6;
    if ((threadIdx.x & 63) == 63) wsum[w] = incl;
    __syncthreads();
    int offset = 0;
    #pragma unroll
    for (int i = 0; i < NW - 1; ++i) offset += (i < w) ? wsum[i] : 0;
    return offset + incl - v;
}

// ---------------- cursor init (fixed bucket bases) + dummy-row zero ----------------

__global__ void init_kernel(int* __restrict__ gcursor, int K,
                            half8* __restrict__ g0, half8* __restrict__ g1,
                            half8* __restrict__ g2, int N) {
    int t = threadIdx.x;
    if (t < K) gcursor[t] = t * BK_CAP;
    if (t < 8) {
        half8 z = (half8)(_Float16)0;
        g0[(size_t)N * 8 + t] = z;
        g1[(size_t)N * 8 + t] = z;
        g2[(size_t)N * 8 + t] = z;
    }
}

// ---------------- Phase A: partition edges into K coarse buckets ----------------
// Record: src (17b) | dst_local (9b) << 17  — fits 4B for N < 131072.

__global__ void part_kernel(const int* __restrict__ src, const int* __restrict__ dst,
                            int* __restrict__ gcursor, unsigned int* __restrict__ part,
                            int E, int K) {
    __shared__ unsigned int tmp_rec[PART_T];
    __shared__ unsigned char tmp_bkt[PART_T];
    __shared__ int hist[256];
    __shared__ int lstart[256];
    __shared__ int cursor[256];
    __shared__ int gbase[256];
    __shared__ int wsum[4];
    int t = threadIdx.x;
    int tile = blockIdx.x * PART_T;
    int n = E - tile; if (n > PART_T) n = PART_T;

    hist[t] = 0;
    __syncthreads();

    for (int i = t; i < n; i += 256) {
        int s = src[tile + i];
        int d = dst[tile + i];
        int b = d >> BK_SHIFT;
        tmp_rec[i] = (unsigned int)s | ((unsigned int)(d & (BK_SPAN - 1)) << 17);
        tmp_bkt[i] = (unsigned char)b;
        atomicAdd(&hist[b], 1);
    }
    __syncthreads();

    int hv = hist[t];
    int excl = block_scan_excl(hv, wsum);
    lstart[t] = excl;
    cursor[t] = excl;
    if (t < K && hv > 0) gbase[t] = atomicAdd(&gcursor[t], hv);
    __syncthreads();

    for (int i = t; i < n; i += 256) {
        int b = tmp_bkt[i];
        int r = atomicAdd(&cursor[b], 1);
        part[gbase[b] + (r - lstart[b])] = tmp_rec[i];
    }
}

// ---------------- Phase B: per-bucket degree + padded CSR + dis + fused conv ----------------

__global__ __launch_bounds__(CSR_T)
void csr_kernel(const unsigned int* __restrict__ part, const int* __restrict__ gcursor,
                int2* __restrict__ prange, int* __restrict__ csr_src,
                float* __restrict__ dis,
                const float* __restrict__ emb, half8* __restrict__ g0, int N) {
    __shared__ int h[BK_SPAN];        // degree -> placement cursor (relative)
    __shared__ int pfx[BK_SPAN + 1];  // padded exclusive prefix (relative)
    __shared__ float sdis[BK_SPAN];
    __shared__ int wsum[CSR_T / 64];
    int b = blockIdx.x;
    int t = threadIdx.x;
    int pbase = b * BK_CAP;
    int cnt   = gcursor[b] - pbase;
    int qbase = b * BK_REG;
    int nodeBase = b << BK_SHIFT;

    if (t < BK_SPAN) h[t] = 0;
    __syncthreads();

    for (int j = t; j < cnt; j += CSR_T) {
        unsigned int rec = part[pbase + j];
        atomicAdd(&h[rec >> 17], 1);
    }
    __syncthreads();

    int d0 = (t < BK_SPAN) ? h[t] : 0;
    if (t < BK_SPAN) {
        float f0 = d0 > 0 ? rsqrtf((float)d0) : 0.0f;
        int i0 = nodeBase + t;
        if (i0 < N) dis[i0] = f0;
        sdis[t] = f0;
    }
    int p0 = (d0 + 3) & ~3;
    int excl = block_scan_excl_n<CSR_T / 64>(p0, wsum);  // internal __syncthreads
    if (t < BK_SPAN) {
        pfx[t] = excl;
        h[t]   = excl;                // placement cursor (relative start)
    }
    if (t == BK_SPAN - 1) pfx[BK_SPAN] = excl + p0;
    __syncthreads();

    if (t < BK_SPAN) {
        int idx = nodeBase + t;
        if (idx < N) prange[idx] = make_int2(qbase + pfx[t], qbase + pfx[t + 1]);
    }
    __syncthreads();

    for (int j = t; j < cnt; j += CSR_T) {
        unsigned int rec = part[pbase + j];
        int dl = (int)(rec >> 17);
        int s  = (int)(rec & 0x1FFFFu);
        int p = atomicAdd(&h[dl], 1);
        csr_src[qbase + p] = s;
    }
    __syncthreads();

    if (t < BK_SPAN) {
        int endp = pfx[t + 1];
        for (int p = h[t]; p < endp; ++p) csr_src[qbase + p] = N;
    }

    const float4* e4 = (const float4*)emb;
    int nloc = N - nodeBase;
    if (nloc > BK_SPAN) nloc = BK_SPAN;
    if (nloc < 0) nloc = 0;
    int lim = nloc * 8;
    for (int j = t; j < lim; j += CSR_T) {
        int r = j >> 3;
        int v = nodeBase + r;
        float dv = sdis[r];
        float4 a = e4[(size_t)v * 16 + (size_t)(j & 7) * 2];
        float4 c = e4[(size_t)v * 16 + (size_t)(j & 7) * 2 + 1];
        half8 hh;
        hh[0] = (_Float16)(dv * a.x); hh[1] = (_Float16)(dv * a.y);
        hh[2] = (_Float16)(dv * a.z); hh[3] = (_Float16)(dv * a.w);
        hh[4] = (_Float16)(dv * c.x); hh[5] = (_Float16)(dv * c.y);
        hh[6] = (_Float16)(dv * c.z); hh[7] = (_Float16)(dv * c.w);
        g0[(size_t)v * 8 + (j & 7)] = hh;
    }
}

// ---------------- layer compute: persistent grid-stride, 1-ahead prange prefetch ----------------

__device__ __forceinline__ void softmax4(const float* __restrict__ alpha, float* w) {
    float a0 = alpha[0], a1 = alpha[1], a2 = alpha[2], a3 = alpha[3];
    float m = fmaxf(fmaxf(a0, a1), fmaxf(a2, a3));
    float e0 = expf(a0 - m), e1 = expf(a1 - m), e2 = expf(a2 - m), e3 = expf(a3 - m);
    float s = 1.0f / (e0 + e1 + e2 + e3);
    w[0] = e0 * s; w[1] = e1 * s; w[2] = e2 * s; w[3] = e3 * s;
}

// SpMM: g_out[v] = dis[v]^2 * sum_{s in N(v)} g_in[s]
// 2 nodes/wave, 4 slots x 8 subs; grid-stride over node pairs with software pipeline.
__global__ __launch_bounds__(256)
void spmm_kernel(const int2* __restrict__ prange, const int* __restrict__ csr_src,
                 const float* __restrict__ dis,
                 const half8* __restrict__ gin, half8* __restrict__ gout,
                 int N, int nwaves) {
    int lane = threadIdx.x & 63;
    int gw = blockIdx.x * (blockDim.x >> 6) + (threadIdx.x >> 6);
    int half = lane >> 5;
    int slot = (lane >> 3) & 3;
    int sub  = lane & 7;
    const int4* csr4 = (const int4*)csr_src;
    int npairs = (N + 1) >> 1;

    int p = gw;
    if (p >= npairs) return;
    int v0 = p * 2 + half;
    int2 pr = (v0 < N) ? prange[v0] : make_int2(0, 0);

    for (; p < npairs; p += nwaves) {
        int v = p * 2 + half;
        // issue next pair's prange early (overlaps with this pair's gathers)
        int pn = p + nwaves;
        int2 prn = make_int2(0, 0);
        if (pn < npairs) {
            int vn = pn * 2 + half;
            if (vn < N) prn = prange[vn];
        }
        half8 acc0 = (half8)(_Float16)0;
        half8 acc1 = (half8)(_Float16)0;
        for (int j = pr.x + slot * 4; j < pr.y; j += 16) {
            int4 c = csr4[j >> 2];
            acc0 = acc0 + gin[c.x * 8 + sub];
            acc1 = acc1 + gin[c.y * 8 + sub];
            acc0 = acc0 + gin[c.z * 8 + sub];
            acc1 = acc1 + gin[c.w * 8 + sub];
        }
        half8 acc = acc0 + acc1;
        acc = acc + dpp_ror8_h8(acc);
        acc = acc + shfl_xor_h8(acc, 16);
        if (v < N && (lane & 31) < 8) {
            float d = dis[v];
            float d2 = d * d;
            half8 o;
            #pragma unroll
            for (int k = 0; k < 8; ++k) o[k] = (_Float16)(d2 * (float)acc[k]);
            gout[v * 8 + sub] = o;
        }
        pr = prn;
    }
}

// last layer + fused combine; out stored fp16
__global__ __launch_bounds__(256)
void spmm_final_kernel(const int2* __restrict__ prange, const int* __restrict__ csr_src,
                       const float* __restrict__ dis,
                       const float* __restrict__ emb, const half8* __restrict__ g1,
                       const half8* __restrict__ g2, half8* __restrict__ out,
                       const float* __restrict__ alpha, int N, int nwaves) {
    int lane = threadIdx.x & 63;
    int gw = blockIdx.x * (blockDim.x >> 6) + (threadIdx.x >> 6);
    int half = lane >> 5;
    int slot = (lane >> 3) & 3;
    int sub  = lane & 7;
    const int4* csr4 = (const int4*)csr_src;
    const float4* e4 = (const float4*)emb;
    int npairs = (N + 1) >> 1;

    float w[4];
    softmax4(alpha, w);                  // uniform, hoisted

    int p = gw;
    if (p >= npairs) return;
    int v0 = p * 2 + half;
    int2 pr = (v0 < N) ? prange[v0] : make_int2(0, 0);

    for (; p < npairs; p += nwaves) {
        int v = p * 2 + half;
        int pn = p + nwaves;
        int2 prn = make_int2(0, 0);
        if (pn < npairs) {
            int vn = pn * 2 + half;
            if (vn < N) prn = prange[vn];
        }
        half8 acc0 = (half8)(_Float16)0;
        half8 acc1 = (half8)(_Float16)0;
        for (int j = pr.x + slot * 4; j < pr.y; j += 16) {
            int4 c = csr4[j >> 2];
            acc0 = acc0 + g2[c.x * 8 + sub];
            acc1 = acc1 + g2[c.y * 8 + sub];
            acc0 = acc0 + g2[c.z * 8 + sub];
            acc1 = acc1 + g2[c.w * 8 + sub];
        }
        half8 acc = acc0 + acc1;
        acc = acc + dpp_ror8_h8(acc);
        acc = acc + shfl_xor_h8(acc, 16);
        if (v < N && (lane & 31) < 8) {
            float d  = dis[v];
            float iv = d > 0.0f ? 1.0f / d : 0.0f;   // invdis = sqrt(deg)
            float4 ea = e4[(size_t)v * 16 + sub * 2];
            float4 eb = e4[(size_t)v * 16 + sub * 2 + 1];
            half8 h1 = g1[v * 8 + sub];
            half8 h2 = g2[v * 8 + sub];
            float ef[8] = {ea.x, ea.y, ea.z, ea.w, eb.x, eb.y, eb.z, eb.w};
            half8 o;
            #pragma unroll
            for (int k = 0; k < 8; ++k) {
                float x1 = (float)h1[k] * iv;
                float x2 = (float)h2[k] * iv;
                float x3 = d * (float)acc[k];
                float val = w[0] * ef[k] + w[1] * x1 + w[2] * x2 + w[3] * x3;
                o[k] = (_Float16)val;
            }
            out[v * 8 + sub] = o;
        }
        pr = prn;
    }
}

// res[e] = dot(out[a[e]], out[b[e]]); grid-stride with 1-ahead index prefetch
__global__ __launch_bounds__(256)
void dot_kernel(const int* __restrict__ a, const int* __restrict__ b,
                const half8* __restrict__ out, float* __restrict__ res,
                int E, int estride) {
    long long g = (long long)blockIdx.x * blockDim.x + threadIdx.x;
    int sub = (int)(g & 7);
    int e = (int)(g >> 3);
    if (e >= E) return;

    int ia = a[e];
    int ib = b[e];
    for (; e < E; e += estride) {
        int en = e + estride;
        int ian = 0, ibn = 0;
        if (en < E) { ian = a[en]; ibn = b[en]; }   // issue early
        half8 va = out[ia * 8 + sub];
        half8 vb = out[ib * 8 + sub];
#if __has_builtin(__builtin_amdgcn_fdot2)
        float v = 0.f;
        v = __builtin_amdgcn_fdot2(__builtin_shufflevector(va, va, 0, 1),
                                   __builtin_shufflevector(vb, vb, 0, 1), v, false);
        v = __builtin_amdgcn_fdot2(__builtin_shufflevector(va, va, 2, 3),
                                   __builtin_shufflevector(vb, vb, 2, 3), v, false);
        v = __builtin_amdgcn_fdot2(__builtin_shufflevector(va, va, 4, 5),
                                   __builtin_shufflevector(vb, vb, 4, 5), v, false);
        v = __builtin_amdgcn_fdot2(__builtin_shufflevector(va, va, 6, 7),
                                   __builtin_shufflevector(vb, vb, 6, 7), v, false);
#else
        float v = 0.f;
        #pragma unroll
        for (int k = 0; k < 8; ++k) v += (float)va[k] * (float)vb[k];
#endif
        v = dpp_sum8_f32(v);
        if (sub == 0) res[e] = v;
        ia = ian; ib = ibn;
    }
}

// ---------------- launcher ----------------

static inline size_t align256(size_t x) { return (x + 255) & ~(size_t)255; }

extern "C" void kernel_launch(void* const* d_in, const int* in_sizes, int n_in,
                              void* d_out, int out_size, void* d_ws, size_t ws_size,
                              hipStream_t stream) {
    const int* edge_index = (const int*)d_in[0];       // [2, E]
    const int* edge_label = (const int*)d_in[1];       // [2, E]
    const float* emb      = (const float*)d_in[2];     // [N, D]
    const float* alpha    = (const float*)d_in[3];     // [L+1]

    const int E = in_sizes[0] / 2;
    const int N = in_sizes[2] / DIM;
    const int K = (N + BK_SPAN - 1) >> BK_SHIFT;       // coarse buckets (<=256)

    const int* src = edge_index;
    const int* dst = edge_index + E;
    const int* la  = edge_label;
    const int* lb  = edge_label + E;

    // workspace layout (~54 MB; outbuf aliases g0 which is dead after layer 1)
    char* ws = (char*)d_ws;
    size_t off = 0;
    float* dis     = (float*)(ws + off); off = align256(off + (size_t)N * 4);
    int2*  prange  = (int2*)(ws + off);  off = align256(off + (size_t)N * 8);
    int*   gcursor = (int*)(ws + off);   off = align256(off + (size_t)256 * 4);
    unsigned int* part = (unsigned int*)(ws + off); off = align256(off + (size_t)K * BK_CAP * 4);
    int*   csr_src = (int*)(ws + off);   off = align256(off + (size_t)K * BK_REG * 4);
    half8* g0      = (half8*)(ws + off); off = align256(off + (size_t)(N + 1) * DIM * 2);
    half8* g1      = (half8*)(ws + off); off = align256(off + (size_t)(N + 1) * DIM * 2);
    half8* g2      = (half8*)(ws + off); off = align256(off + (size_t)(N + 1) * DIM * 2);
    half8* outbuf  = g0;                 // alias: g0 dead after spmm layer 1
    (void)ws_size;

    const int B = 256;
    const int gridT = (E + PART_T - 1) / PART_T;

    // 1. fixed bucket bases + dummy-row zeroing
    init_kernel<<<1, B, 0, stream>>>(gcursor, K, g0, g1, g2, N);

    // 2. Phase A partition (2-pass, direct bucket-span writes)
    part_kernel<<<gridT, B, 0, stream>>>(src, dst, gcursor, part, E, K);

    // 3. Phase B: degree + dis + padded CSR + fused conv (g0)
    csr_kernel<<<K, CSR_T, 0, stream>>>(part, gcursor, prange, csr_src, dis, emb, g0, N);

    // 4. three gather-SpMM layers, persistent grid-stride + pipelined prefetch
    const int nwavesS = GRID_G * (B / 64);
    spmm_kernel<<<GRID_G, B, 0, stream>>>(prange, csr_src, dis, g0, g1, N, nwavesS);
    spmm_kernel<<<GRID_G, B, 0, stream>>>(prange, csr_src, dis, g1, g2, N, nwavesS);
    spmm_final_kernel<<<GRID_G, B, 0, stream>>>(prange, csr_src, dis, emb, g1, g2,
                                                outbuf, alpha, N, nwavesS);

    // 5. per-edge dot products, persistent grid-stride + index prefetch
    const int estride = (GRID_G * B) >> 3;
    dot_kernel<<<GRID_G, B, 0, stream>>>(la, lb, outbuf, (float*)d_out, E, estride);
}